// Round 1
// baseline (78.736 us; speedup 1.0000x reference)
//
#include <hip/hip_runtime.h>

#define EPS_C 0.0009f   // 0.03^2

__device__ __forceinline__ float metric_val(float dot, float f, float g) {
    float c    = dot / (f * g);
    float dn   = sqrtf(fmaxf(2.0f - 2.0f * c, 0.0f));
    float dist = (2.0f - dn) * 0.5f;
    float lum  = (2.0f * f * g + EPS_C) / (f * f + g * g + EPS_C);
    float met  = dist * sqrtf(lum);
    return (1.0f - met) * 2.0f;
}

// Grid: 256 blocks x 256 threads.
//   bg = blockIdx >> 5  (8 groups of 8 batch rows; wave w owns b = bg*8 + 2w, +1)
//   mg = blockIdx & 31  (32 groups of 8 modes; XCD-affine so same-mode blocks share L2)
// Each wave keeps its 2 input rows fully in registers (2 x 16 float4),
// streams each 16KB mode row once, accumulating dot(b0), dot(b1) and mode
// sum-of-squares in one pass. Butterfly shuffle reduces across 64 lanes.
__global__ __launch_bounds__(256, 1)
void simk_main(const float* __restrict__ inputs, const float* __restrict__ modes,
               float* __restrict__ out) {
    const int tid  = threadIdx.x;
    const int lane = tid & 63;
    const int w    = tid >> 6;
    const int bg   = blockIdx.x >> 5;
    const int mg   = blockIdx.x & 31;
    const int b0   = bg * 8 + w * 2;
    const int b1   = b0 + 1;

    const float4* inp4 = (const float4*)inputs;
    const float4* mod4 = (const float4*)modes;

    // Input rows in registers: element float4 index = j*64 + lane (coalesced 1KB/step)
    float4 in0[16], in1[16];
#pragma unroll
    for (int j = 0; j < 16; ++j) in0[j] = inp4[(size_t)b0 * 1024 + j * 64 + lane];
#pragma unroll
    for (int j = 0; j < 16; ++j) in1[j] = inp4[(size_t)b1 * 1024 + j * 64 + lane];

    // Input Frobenius norms
    float s0 = 0.f, s1 = 0.f;
#pragma unroll
    for (int j = 0; j < 16; ++j) {
        s0 += in0[j].x * in0[j].x + in0[j].y * in0[j].y + in0[j].z * in0[j].z + in0[j].w * in0[j].w;
        s1 += in1[j].x * in1[j].x + in1[j].y * in1[j].y + in1[j].z * in1[j].z + in1[j].w * in1[j].w;
    }
#pragma unroll
    for (int sh = 1; sh < 64; sh <<= 1) {
        s0 += __shfl_xor(s0, sh, 64);
        s1 += __shfl_xor(s1, sh, 64);
    }
    const float f0 = sqrtf(s0);
    const float f1 = sqrtf(s1);

    float min0 = 3.0e38f, min1 = 3.0e38f;

    for (int mi = 0; mi < 8; ++mi) {
        const int m = mg * 8 + mi;
        const float4* mp = mod4 + (size_t)m * 1024;

        // 12 independent FMA chains for ILP
        float d0x = 0.f, d0y = 0.f, d0z = 0.f, d0w = 0.f;
        float d1x = 0.f, d1y = 0.f, d1z = 0.f, d1w = 0.f;
        float qx  = 0.f, qy  = 0.f, qz  = 0.f, qw  = 0.f;
#pragma unroll
        for (int j = 0; j < 16; ++j) {
            float4 v = mp[j * 64 + lane];
            d0x += v.x * in0[j].x; d0y += v.y * in0[j].y;
            d0z += v.z * in0[j].z; d0w += v.w * in0[j].w;
            d1x += v.x * in1[j].x; d1y += v.y * in1[j].y;
            d1z += v.z * in1[j].z; d1w += v.w * in1[j].w;
            qx  += v.x * v.x;      qy  += v.y * v.y;
            qz  += v.z * v.z;      qw  += v.w * v.w;
        }
        float d0 = (d0x + d0y) + (d0z + d0w);
        float d1 = (d1x + d1y) + (d1z + d1w);
        float q  = (qx + qy) + (qz + qw);
#pragma unroll
        for (int sh = 1; sh < 64; sh <<= 1) {
            d0 += __shfl_xor(d0, sh, 64);
            d1 += __shfl_xor(d1, sh, 64);
            q  += __shfl_xor(q,  sh, 64);
        }
        const float g = sqrtf(q);
        min0 = fminf(min0, metric_val(d0, f0, g));
        min1 = fminf(min1, metric_val(d1, f1, g));
    }

    // Positive floats order identically as ints -> atomicMin on bit pattern.
    if (lane == 0) {
        atomicMin((int*)(out + b0), __float_as_int(min0));
        atomicMin((int*)(out + b1), __float_as_int(min1));
    }
}

extern "C" void kernel_launch(void* const* d_in, const int* in_sizes, int n_in,
                              void* d_out, int out_size, void* d_ws, size_t ws_size,
                              hipStream_t stream) {
    const float* inputs = (const float*)d_in[0];
    const float* modes  = (const float*)d_in[1];
    float* out = (float*)d_out;

    // Init out[b] to +3.39e38 (0x7F7F7F7F): positive, larger than any metric value.
    hipMemsetAsync(d_out, 0x7F, (size_t)out_size * sizeof(float), stream);
    simk_main<<<256, 256, 0, stream>>>(inputs, modes, out);
}

// Round 2
// 70.724 us; speedup vs baseline: 1.1133x; 1.1133x over previous
//
#include <hip/hip_runtime.h>

#define EPS_C 0.0009f   // 0.03^2

__device__ __forceinline__ float metric_val(float dot, float f, float g) {
    float c    = dot / (f * g);
    float dn   = sqrtf(fmaxf(2.0f - 2.0f * c, 0.0f));
    float dist = (2.0f - dn) * 0.5f;
    float lum  = (2.0f * f * g + EPS_C) / (f * f + g * g + EPS_C);
    float met  = dist * sqrtf(lum);
    return (1.0f - met) * 2.0f;
}

// Grid: 256 blocks x 256 threads.
//   bg = blockIdx >> 5  (8 groups of 8 batch rows; wave w owns b = bg*8 + 2w, +1)
//   mg = blockIdx & 31  (32 groups of 8 modes; XCD-affine so same-mode blocks share L2)
// Each wave keeps its 2 input rows fully in registers (2 x 16 float4),
// streams each 16KB mode row once, accumulating dot(b0), dot(b1) and mode
// sum-of-squares in one pass. Butterfly shuffle reduces across 64 lanes.
// Partial mins go to ws[mg*64 + b] (all 2048 slots written every call ->
// immune to the 0xAA ws-poison); simk_reduce folds the 32 partials per row.
__global__ __launch_bounds__(256, 1)
void simk_main(const float* __restrict__ inputs, const float* __restrict__ modes,
               float* __restrict__ ws) {
    const int tid  = threadIdx.x;
    const int lane = tid & 63;
    const int w    = tid >> 6;
    const int bg   = blockIdx.x >> 5;
    const int mg   = blockIdx.x & 31;
    const int b0   = bg * 8 + w * 2;
    const int b1   = b0 + 1;

    const float4* inp4 = (const float4*)inputs;
    const float4* mod4 = (const float4*)modes;

    // Input rows in registers: element float4 index = j*64 + lane (coalesced 1KB/step)
    float4 in0[16], in1[16];
#pragma unroll
    for (int j = 0; j < 16; ++j) in0[j] = inp4[(size_t)b0 * 1024 + j * 64 + lane];
#pragma unroll
    for (int j = 0; j < 16; ++j) in1[j] = inp4[(size_t)b1 * 1024 + j * 64 + lane];

    // Input Frobenius norms
    float s0 = 0.f, s1 = 0.f;
#pragma unroll
    for (int j = 0; j < 16; ++j) {
        s0 += in0[j].x * in0[j].x + in0[j].y * in0[j].y + in0[j].z * in0[j].z + in0[j].w * in0[j].w;
        s1 += in1[j].x * in1[j].x + in1[j].y * in1[j].y + in1[j].z * in1[j].z + in1[j].w * in1[j].w;
    }
#pragma unroll
    for (int sh = 1; sh < 64; sh <<= 1) {
        s0 += __shfl_xor(s0, sh, 64);
        s1 += __shfl_xor(s1, sh, 64);
    }
    const float f0 = sqrtf(s0);
    const float f1 = sqrtf(s1);

    float min0 = 3.0e38f, min1 = 3.0e38f;

    for (int mi = 0; mi < 8; ++mi) {
        const int m = mg * 8 + mi;
        const float4* mp = mod4 + (size_t)m * 1024;

        // 12 independent FMA chains for ILP
        float d0x = 0.f, d0y = 0.f, d0z = 0.f, d0w = 0.f;
        float d1x = 0.f, d1y = 0.f, d1z = 0.f, d1w = 0.f;
        float qx  = 0.f, qy  = 0.f, qz  = 0.f, qw  = 0.f;
#pragma unroll
        for (int j = 0; j < 16; ++j) {
            float4 v = mp[j * 64 + lane];
            d0x += v.x * in0[j].x; d0y += v.y * in0[j].y;
            d0z += v.z * in0[j].z; d0w += v.w * in0[j].w;
            d1x += v.x * in1[j].x; d1y += v.y * in1[j].y;
            d1z += v.z * in1[j].z; d1w += v.w * in1[j].w;
            qx  += v.x * v.x;      qy  += v.y * v.y;
            qz  += v.z * v.z;      qw  += v.w * v.w;
        }
        float d0 = (d0x + d0y) + (d0z + d0w);
        float d1 = (d1x + d1y) + (d1z + d1w);
        float q  = (qx + qy) + (qz + qw);
#pragma unroll
        for (int sh = 1; sh < 64; sh <<= 1) {
            d0 += __shfl_xor(d0, sh, 64);
            d1 += __shfl_xor(d1, sh, 64);
            q  += __shfl_xor(q,  sh, 64);
        }
        const float g = sqrtf(q);
        min0 = fminf(min0, metric_val(d0, f0, g));
        min1 = fminf(min1, metric_val(d1, f1, g));
    }

    // Deterministic partial write: each (b, mg) slot written by exactly one wave.
    if (lane == 0) {
        ws[mg * 64 + b0] = min0;
        ws[mg * 64 + b1] = min1;
    }
}

// One wave: thread b folds the 32 mode-group partials for batch row b.
__global__ void simk_reduce(const float* __restrict__ ws, float* __restrict__ out) {
    const int b = threadIdx.x;
    float m = 3.0e38f;
#pragma unroll
    for (int mg = 0; mg < 32; ++mg) m = fminf(m, ws[mg * 64 + b]);
    out[b] = m;
}

extern "C" void kernel_launch(void* const* d_in, const int* in_sizes, int n_in,
                              void* d_out, int out_size, void* d_ws, size_t ws_size,
                              hipStream_t stream) {
    const float* inputs = (const float*)d_in[0];
    const float* modes  = (const float*)d_in[1];
    float* ws  = (float*)d_ws;
    float* out = (float*)d_out;

    simk_main<<<256, 256, 0, stream>>>(inputs, modes, ws);
    simk_reduce<<<1, 64, 0, stream>>>(ws, out);
}